// Round 10
// baseline (2341.526 us; speedup 1.0000x reference)
//
#include <hip/hip_runtime.h>
#include <hip/hip_bf16.h>

// Compiler-only memory fence: same-wave DS ops are processed in order by HW
// (LLVM's wavefront-scope fence emits nothing), so all we must prevent is
// compiler reordering of type-punned LDS accesses across phase boundaries.
#define WAVE_FENCE() asm volatile("" ::: "memory")

namespace {

using bf16x8 = __attribute__((ext_vector_type(8))) short;
using f32x4  = __attribute__((ext_vector_type(4))) float;

constexpr int NL = 9, BB = 8192;
constexpr int WPB = 8;            // waves per block; wave = one sequence
constexpr int NT = 64 * WPB;      // 512 threads

// Per-wave LDS region (bytes). No cross-wave sharing -> no barriers.
constexpr int WV_F1 = 0;          // fp32 [7][64] swizzled (32B granule)
constexpr int WV_F2 = 1792;
constexpr int WV_SQ = 3584;
constexpr int WV_QB = 5376;       // bf16 [7][64] swizzled (Q/ctx/hidden)
constexpr int WV_KB = 6272;       // bf16 [15][64] swizzled (K; CA: f1 0..6, f2 8..14)
constexpr int WV_VT = 8192;       // bf16 V^T [64 d][16 kv] plain (d*32 + kv*2)
constexpr int WVSZ  = 10240;
constexpr int SMEM_TOTAL = WVSZ * WPB;   // 81920 -> 2 blocks/CU

__device__ __forceinline__ unsigned short f2bf(float f) {
  union { __hip_bfloat16 h; unsigned short s; } u;
  u.h = __float2bfloat16(f);
  return u.s;
}
__device__ __forceinline__ uint32_t pk2(float a, float b) {
  return (uint32_t)f2bf(a) | ((uint32_t)f2bf(b) << 16);
}
__device__ __forceinline__ int swzS(int r, int c) {   // fp32 [*][64]
  return r * 256 + ((((c >> 3) ^ (r & 7)) << 5) | ((c & 7) << 2));
}
__device__ __forceinline__ int swzB(int r, int c) {   // bf16 [*][64]
  return r * 128 + ((((c >> 3) ^ (r & 7)) << 4) | ((c & 7) << 1));
}

// fp32 swizzled state row -> bf16x8 fragment (8 consecutive k, k0 % 8 == 0)
__device__ __forceinline__ bf16x8 ldStateFrag(const char* base, int r, int k0) {
  const float4* p = (const float4*)(base + r * 256 + (((k0 >> 3) ^ (r & 7)) << 5));
  float4 x = p[0], y = p[1];
  union { bf16x8 v; uint32_t u[4]; } o;
  o.u[0] = pk2(x.x, x.y); o.u[1] = pk2(x.z, x.w);
  o.u[2] = pk2(y.x, y.y); o.u[3] = pk2(y.z, y.w);
  return o.v;
}
// bf16 LDS fragment load via uint2 (the SAME type the stores use -> no TBAA
// mismatch, compiler cannot claim no-alias and reorder across phases).
__device__ __forceinline__ bf16x8 ldBfFrag(const char* base, int r, int k0) {
  const uint2* p = (const uint2*)(base + r * 128 + (((k0 >> 3) ^ (r & 7)) << 4));
  const uint2 a = p[0], b = p[1];
  union { bf16x8 v; uint32_t u[4]; } o;
  o.u[0] = a.x; o.u[1] = a.y; o.u[2] = b.x; o.u[3] = b.y;
  return o.v;
}

// Per-wave GEMM, fully scalarized fragments (no arrays -> no scratch).
// Normal tiles (nt < VNT): D = W x state^T (lane: token col q, 4 feature rows).
// V tiles (nt >= VNT):     D = state x W^T (lane: feature col, 4 token rows).
// LDK tied to KF: 64 for KF=2, 32 for KF=1.
template <int NTOT, int KF, int VNT, bool WS, class BLD, class STN, class STV>
__device__ __forceinline__ void gemmw(const short* __restrict__ wbf,
                                      const float* __restrict__ wf,
                                      const float* __restrict__ biasN,
                                      const float* __restrict__ biasV,
                                      int q, int gI, BLD bld, STN stn, STV stv)
{
  constexpr int LDK = (KF == 2) ? 64 : 32;
  const bf16x8 b0 = bld(q, gI * 8);
  bf16x8 b1 = b0;
  if constexpr (KF == 2) b1 = bld(q, 32 + gI * 8);
#pragma unroll
  for (int nt = 0; nt < NTOT; ++nt) {
    const int row = nt * 16 + q;
    bf16x8 a0, a1;
    if constexpr (WS) {
      a0 = *(const bf16x8*)(wbf + row * LDK + gI * 8);
      if constexpr (KF == 2)
        a1 = *(const bf16x8*)(wbf + row * LDK + 32 + gI * 8);
    } else {
      {
        const float* wp = wf + row * LDK + gI * 8;
        float4 x = *(const float4*)wp, y = *(const float4*)(wp + 4);
        union { bf16x8 v; uint32_t u[4]; } o;
        o.u[0] = pk2(x.x, x.y); o.u[1] = pk2(x.z, x.w);
        o.u[2] = pk2(y.x, y.y); o.u[3] = pk2(y.z, y.w);
        a0 = o.v;
      }
      a1 = a0;
      if constexpr (KF == 2) {
        const float* wp = wf + row * LDK + 32 + gI * 8;
        float4 x = *(const float4*)wp, y = *(const float4*)(wp + 4);
        union { bf16x8 v; uint32_t u[4]; } o;
        o.u[0] = pk2(x.x, x.y); o.u[1] = pk2(x.z, x.w);
        o.u[2] = pk2(y.x, y.y); o.u[3] = pk2(y.z, y.w);
        a1 = o.v;
      }
    }
    if (nt < VNT) {
      const float4 b4 = *(const float4*)(biasN + nt * 16 + gI * 4);
      f32x4 acc = { b4.x, b4.y, b4.z, b4.w };
      acc = __builtin_amdgcn_mfma_f32_16x16x32_bf16(a0, b0, acc, 0, 0, 0);
      if constexpr (KF == 2)
        acc = __builtin_amdgcn_mfma_f32_16x16x32_bf16(a1, b1, acc, 0, 0, 0);
      stn(nt, acc);
    } else {
      const float bv = biasV[(nt - VNT) * 16 + q];
      f32x4 acc = { bv, bv, bv, bv };
      acc = __builtin_amdgcn_mfma_f32_16x16x32_bf16(b0, a0, acc, 0, 0, 0);
      if constexpr (KF == 2)
        acc = __builtin_amdgcn_mfma_f32_16x16x32_bf16(b1, a1, acc, 0, 0, 0);
      stv(nt - VNT, acc);
    }
  }
}

// Per-wave attention over 4 heads. kb rows / vt slots: SA 0..6;
// CA f1 -> 0..6, f2 -> 8..14 (slots 7,15 masked by P=0; finite garbage ok).
template <bool CA_>
__device__ __forceinline__ void attnw(char* qb, const char* kb, const char* vt,
                                      int q, int gI)
{
  constexpr int KCL = CA_ ? 14 : 6;
#pragma unroll
  for (int h = 0; h < 4; ++h) {
    bf16x8 kfrag = {}, qfrag = {};
    if (gI < 2) {
      qfrag = ldBfFrag(qb, q > 6 ? 6 : q, h * 16 + gI * 8);
      kfrag = ldBfFrag(kb, q > KCL ? KCL : q, h * 16 + gI * 8);
    }
    f32x4 s = { 0.f, 0.f, 0.f, 0.f };
    s = __builtin_amdgcn_mfma_f32_16x16x32_bf16(kfrag, qfrag, s, 0, 0, 0);

    float e0, e1, e2, e3, sum;
    {
      const int k0 = gI * 4;
      const float t0 = fminf(s[0] * 0.36067376f, 60.f);   // *0.25 * log2(e)
      const float t1 = fminf(s[1] * 0.36067376f, 60.f);
      const float t2 = fminf(s[2] * 0.36067376f, 60.f);
      const float t3 = fminf(s[3] * 0.36067376f, 60.f);
      const bool v0 = CA_ ? (((k0 + 0) & 7) < 7) : (k0 + 0 < 7);
      const bool v1 = CA_ ? (((k0 + 1) & 7) < 7) : (k0 + 1 < 7);
      const bool v2 = CA_ ? (((k0 + 2) & 7) < 7) : (k0 + 2 < 7);
      const bool v3 = CA_ ? (((k0 + 3) & 7) < 7) : (k0 + 3 < 7);
      e0 = v0 ? exp2f(t0) : 0.f;
      e1 = v1 ? exp2f(t1) : 0.f;
      e2 = v2 ? exp2f(t2) : 0.f;
      e3 = v3 ? exp2f(t3) : 0.f;
      sum = e0 + e1 + e2 + e3;
    }
    sum += __shfl_xor(sum, 16);
    sum += __shfl_xor(sum, 32);
    const float inv = __builtin_amdgcn_rcpf(sum);

    union { bf16x8 v; uint32_t u[4]; } pb;
    pb.u[0] = pk2(e0 * inv, e1 * inv);
    pb.u[1] = pk2(e2 * inv, e3 * inv);
    pb.u[2] = 0; pb.u[3] = 0;

    const int d = h * 16 + q;
    const uint2 vv = *(const uint2*)(vt + d * 32 + gI * 8);
    union { bf16x8 v; uint32_t u[4]; } va;
    va.u[0] = vv.x; va.u[1] = vv.y; va.u[2] = 0; va.u[3] = 0;

    f32x4 o = { 0.f, 0.f, 0.f, 0.f };
    o = __builtin_amdgcn_mfma_f32_16x16x32_bf16(va.v, pb.v, o, 0, 0, 0);

    if (q < 7) {
      *(uint2*)(qb + swzB(q, h * 16 + gI * 4)) =
          make_uint2(pk2(o[0], o[1]), pk2(o[2], o[3]));
    }
  }
}

// Self-attention block: ST updated in place. No barriers (wave-private LDS);
// WAVE_FENCE() pins compiler ordering at each produce->consume boundary.
template <bool WS>
__device__ __forceinline__ void sa_blockw(char* ST, char* qb, char* kb, char* vt,
    const short* Wi, const float* Fi, const float* Bi,
    const short* Wo, const float* Fo, const float* Bo, int q, int gI)
{
  auto bld = [&](int r, int k0) { return ldStateFrag(ST, r > 6 ? 6 : r, k0); };
  auto stn = [&](int nt, f32x4 a) {
    if (q >= 7) return;
    const uint2 v = make_uint2(pk2(a[0], a[1]), pk2(a[2], a[3]));
    if (nt < 4) *(uint2*)(qb + swzB(q, nt * 16 + gI * 4)) = v;
    else        *(uint2*)(kb + swzB(q, (nt - 4) * 16 + gI * 4)) = v;
  };
  auto stv = [&](int ntv, f32x4 a) {   // all 16 slots written; >6 masked later
    const int d = ntv * 16 + q;
    *(uint2*)(vt + d * 32 + gI * 8) = make_uint2(pk2(a[0], a[1]), pk2(a[2], a[3]));
  };
  gemmw<12, 2, 8, WS>(Wi, Fi, Bi, Bi + 128, q, gI, bld, stn, stv);
  WAVE_FENCE();
  attnw<false>(qb, kb, vt, q, gI);
  WAVE_FENCE();
  auto bldc = [&](int r, int k0) { return ldBfFrag(qb, r > 6 ? 6 : r, k0); };
  auto stres = [&](int nt, f32x4 a) {
    if (q >= 7) return;
    const int c0 = nt * 16 + gI * 4;
    float4* p = (float4*)(ST + q * 256 + (((c0 >> 3) ^ (q & 7)) << 5) + ((c0 & 7) << 2));
    float4 v = *p;
    v.x += a[0]; v.y += a[1]; v.z += a[2]; v.w += a[3];
    *p = v;
  };
  auto dum = [](int, f32x4) {};
  gemmw<4, 2, 4, WS>(Wo, Fo, Bo, Bo, q, gI, bldc, stres, dum);
  WAVE_FENCE();
}

// CA K/V projection from one source state (SRC = 0: f1, 1: f2).
template <bool WS, int SRC>
__device__ __forceinline__ void ca_kvw(const char* SS, char* kb, char* vt,
    const short* Wi, const float* Fi, const float* Bi, int q, int gI)
{
  auto bld = [&](int r, int k0) { return ldStateFrag(SS, r > 6 ? 6 : r, k0); };
  auto stk = [&](int nt, f32x4 a) {
    if (q >= 7) return;
    *(uint2*)(kb + swzB(q + SRC * 8, nt * 16 + gI * 4)) =
        make_uint2(pk2(a[0], a[1]), pk2(a[2], a[3]));
  };
  auto stv = [&](int ntv, f32x4 a) {
    if (gI >= 2) return;                 // tokens 0..7 only
    const int d = ntv * 16 + q;
    *(uint2*)(vt + d * 32 + gI * 8 + SRC * 16) =
        make_uint2(pk2(a[0], a[1]), pk2(a[2], a[3]));
  };
  gemmw<8, 2, 4, WS>(Wi + 4096, Fi + 4096, Bi + 64, Bi + 128, q, gI, bld, stk, stv);
}

template <bool WS>
__global__ __launch_bounds__(NT, 4) void pose_kernel(
    const float* __restrict__ feature1, const float* __restrict__ feature2,
    const float* __restrict__ sa1_win, const float* __restrict__ sa1_bin,
    const float* __restrict__ sa1_wout, const float* __restrict__ sa1_bout,
    const float* __restrict__ sa2_win, const float* __restrict__ sa2_bin,
    const float* __restrict__ sa2_wout, const float* __restrict__ sa2_bout,
    const float* __restrict__ ca_win, const float* __restrict__ ca_bin,
    const float* __restrict__ ca_wout, const float* __restrict__ ca_bout,
    const float* __restrict__ ff_w1, const float* __restrict__ ff_b1,
    const float* __restrict__ ff_w2, const float* __restrict__ ff_b2,
    const float* __restrict__ query_embed,
    const float* __restrict__ fc_rot_w, const float* __restrict__ fc_rot_b,
    const float* __restrict__ fc_trans_w, const float* __restrict__ fc_trans_b,
    const short* __restrict__ wbf, float* __restrict__ out)
{
  extern __shared__ char smem[];
  const int t = threadIdx.x;
  const int wid = t >> 6, lane = t & 63;
  const int q = lane & 15, gI = lane >> 4;
  const int bi = blockIdx.y;
  const int sidx = blockIdx.x * WPB + wid;     // this wave's sequence

  char* wb = smem + wid * WVSZ;
  char* F1_ = wb + WV_F1;
  char* F2_ = wb + WV_F2;
  char* SQ_ = wb + WV_SQ;
  char* qb  = wb + WV_QB;
  char* kb  = wb + WV_KB;
  char* vt  = wb + WV_VT;

  // zero-init qb/kb/vt (finite garbage required for masked MFMA inputs)
  {
    const uint4 z = { 0, 0, 0, 0 };
    for (int i = lane; i < 304; i += 64) ((uint4*)(wb + WV_QB))[i] = z;
  }
  // load this wave's sequence state (448 contiguous floats each)
  {
    const float* f1p = feature1 + (size_t)sidx * 448;
    const float* f2p = feature2 + (size_t)sidx * 448;
    const float* qe  = query_embed + (size_t)bi * 448;
    for (int i = lane; i < 448; i += 64) {
      const int r = i >> 6, c = i & 63;
      *(float*)(F1_ + swzS(r, c)) = f1p[i];
      *(float*)(F2_ + swzS(r, c)) = f2p[i];
      *(float*)(SQ_ + swzS(r, c)) = qe[i];
    }
  }
  WAVE_FENCE();   // region is wave-private; HW DS ops are in-order per wave

  auto dum = [](int, f32x4) {};

  for (int li = 0; li < NL; ++li) {
    const int wo = bi * NL + li;

    sa_blockw<WS>(F1_, qb, kb, vt,
                  wbf + wo * 12288,          sa1_win + wo * 12288,  sa1_bin + wo * 192,
                  wbf + 663552 + wo * 4096,  sa1_wout + wo * 4096,  sa1_bout + wo * 64,
                  q, gI);
    sa_blockw<WS>(F2_, qb, kb, vt,
                  wbf + 221184 + wo * 12288, sa2_win + wo * 12288,  sa2_bin + wo * 192,
                  wbf + 737280 + wo * 4096,  sa2_wout + wo * 4096,  sa2_bout + wo * 64,
                  q, gI);

    // ---------- cross-attention ----------
    {
      const short* Wi = wbf + 442368 + wo * 12288;
      const float* Fi = ca_win + wo * 12288;
      const float* Bi = ca_bin + wo * 192;
      auto bldq = [&](int r, int k0) { return ldStateFrag(SQ_, r > 6 ? 6 : r, k0); };
      auto stq = [&](int nt, f32x4 a) {
        if (q >= 7) return;
        *(uint2*)(qb + swzB(q, nt * 16 + gI * 4)) =
            make_uint2(pk2(a[0], a[1]), pk2(a[2], a[3]));
      };
      gemmw<4, 2, 4, WS>(Wi, Fi, Bi, Bi, q, gI, bldq, stq, dum);
      ca_kvw<WS, 0>(F1_, kb, vt, Wi, Fi, Bi, q, gI);
      ca_kvw<WS, 1>(F2_, kb, vt, Wi, Fi, Bi, q, gI);
      WAVE_FENCE();
      attnw<true>(qb, kb, vt, q, gI);
      WAVE_FENCE();
      auto bldc = [&](int r, int k0) { return ldBfFrag(qb, r > 6 ? 6 : r, k0); };
      auto stres = [&](int nt, f32x4 a) {
        if (q >= 7) return;
        const int c0 = nt * 16 + gI * 4;
        float4* p = (float4*)(SQ_ + q * 256 + (((c0 >> 3) ^ (q & 7)) << 5) + ((c0 & 7) << 2));
        float4 v = *p;
        v.x += a[0]; v.y += a[1]; v.z += a[2]; v.w += a[3];
        *p = v;
      };
      gemmw<4, 2, 4, WS>(wbf + 811008 + wo * 4096, ca_wout + wo * 4096,
                         ca_bout + wo * 64, ca_bout + wo * 64, q, gI, bldc, stres, dum);
      WAVE_FENCE();
    }

    // ---------- FFN ----------
    {
      auto bldq = [&](int r, int k0) { return ldStateFrag(SQ_, r > 6 ? 6 : r, k0); };
      auto sth = [&](int nt, f32x4 a) {   // relu -> qb cols 0..31
        if (q >= 7) return;
        *(uint2*)(qb + swzB(q, nt * 16 + gI * 4)) =
            make_uint2(pk2(fmaxf(a[0], 0.f), fmaxf(a[1], 0.f)),
                       pk2(fmaxf(a[2], 0.f), fmaxf(a[3], 0.f)));
      };
      gemmw<2, 2, 2, WS>(wbf + 884736 + wo * 2048, ff_w1 + wo * 2048,
                         ff_b1 + wo * 32, ff_b1 + wo * 32, q, gI, bldq, sth, dum);
      WAVE_FENCE();
      auto bldh = [&](int r, int k0) { return ldBfFrag(qb, r > 6 ? 6 : r, k0); };
      auto stres = [&](int nt, f32x4 a) {
        if (q >= 7) return;
        const int c0 = nt * 16 + gI * 4;
        float4* p = (float4*)(SQ_ + q * 256 + (((c0 >> 3) ^ (q & 7)) << 5) + ((c0 & 7) << 2));
        float4 v = *p;
        v.x += a[0]; v.y += a[1]; v.z += a[2]; v.w += a[3];
        *p = v;
      };
      gemmw<4, 1, 4, WS>(wbf + 921600 + wo * 2048, ff_w2 + wo * 2048,
                         ff_b2 + wo * 64, ff_b2 + wo * 64, q, gI, bldh, stres, dum);
      WAVE_FENCE();
    }
  }

  // ---------- pose head (per wave, shfl reduction) ----------
  {
    float cs = 0.f;
#pragma unroll
    for (int s = 0; s < 7; ++s) cs += *(const float*)(SQ_ + swzS(s, lane));
    const int ncols = bi ? 3 : 4;
    const float* W  = bi ? fc_trans_w : fc_rot_w;
    const float* Bv = bi ? fc_trans_b : fc_rot_b;
    for (int cc = 0; cc < ncols; ++cc) {
      float p = cs * W[cc * 64 + lane];
      p += __shfl_xor(p, 1);  p += __shfl_xor(p, 2);  p += __shfl_xor(p, 4);
      p += __shfl_xor(p, 8);  p += __shfl_xor(p, 16); p += __shfl_xor(p, 32);
      if (lane == 0)
        out[(size_t)sidx * 7 + (bi ? 4 : 0) + cc] = p * (1.f / 7.f) + Bv[cc];
    }
  }
}

// Convert all weight matrices fp32 -> bf16 into workspace (once per call).
__global__ void prep_kernel(const float* __restrict__ a0, const float* __restrict__ a1,
                            const float* __restrict__ a2, const float* __restrict__ a3,
                            const float* __restrict__ a4, const float* __restrict__ a5,
                            const float* __restrict__ a6, const float* __restrict__ a7,
                            short* __restrict__ dst)
{
  for (int i = blockIdx.x * blockDim.x + threadIdx.x; i < 958464;
       i += gridDim.x * blockDim.x) {
    const float* s; int j;
    if      (i < 221184) { s = a0; j = i; }
    else if (i < 442368) { s = a1; j = i - 221184; }
    else if (i < 663552) { s = a2; j = i - 442368; }
    else if (i < 737280) { s = a3; j = i - 663552; }
    else if (i < 811008) { s = a4; j = i - 737280; }
    else if (i < 884736) { s = a5; j = i - 811008; }
    else if (i < 921600) { s = a6; j = i - 884736; }
    else                 { s = a7; j = i - 921600; }
    dst[i] = (short)f2bf(s[j]);
  }
}

} // namespace

extern "C" void kernel_launch(void* const* d_in, const int* in_sizes, int n_in,
                              void* d_out, int out_size, void* d_ws, size_t ws_size,
                              hipStream_t stream)
{
  const float* feature1    = (const float*)d_in[0];
  const float* feature2    = (const float*)d_in[1];
  const float* sa1_win     = (const float*)d_in[2];
  const float* sa1_bin     = (const float*)d_in[3];
  const float* sa1_wout    = (const float*)d_in[4];
  const float* sa1_bout    = (const float*)d_in[5];
  const float* sa2_win     = (const float*)d_in[6];
  const float* sa2_bin     = (const float*)d_in[7];
  const float* sa2_wout    = (const float*)d_in[8];
  const float* sa2_bout    = (const float*)d_in[9];
  const float* ca_win      = (const float*)d_in[10];
  const float* ca_bin      = (const float*)d_in[11];
  const float* ca_wout     = (const float*)d_in[12];
  const float* ca_bout     = (const float*)d_in[13];
  const float* ff_w1       = (const float*)d_in[14];
  const float* ff_b1       = (const float*)d_in[15];
  const float* ff_w2       = (const float*)d_in[16];
  const float* ff_b2       = (const float*)d_in[17];
  const float* query_embed = (const float*)d_in[18];
  const float* fc_rot_w    = (const float*)d_in[19];
  const float* fc_rot_b    = (const float*)d_in[20];
  const float* fc_trans_w  = (const float*)d_in[21];
  const float* fc_trans_b  = (const float*)d_in[22];

  const bool ws_ok = (d_ws != nullptr) && (ws_size >= (size_t)958464 * 2);
  dim3 grid(BB / WPB, 2);

  if (ws_ok) {
    prep_kernel<<<dim3(936), 512, 0, stream>>>(sa1_win, sa2_win, ca_win,
                                               sa1_wout, sa2_wout, ca_wout,
                                               ff_w1, ff_w2, (short*)d_ws);
    hipFuncSetAttribute(reinterpret_cast<const void*>(&pose_kernel<true>),
                        hipFuncAttributeMaxDynamicSharedMemorySize, SMEM_TOTAL);
    pose_kernel<true><<<grid, NT, SMEM_TOTAL, stream>>>(
        feature1, feature2,
        sa1_win, sa1_bin, sa1_wout, sa1_bout,
        sa2_win, sa2_bin, sa2_wout, sa2_bout,
        ca_win, ca_bin, ca_wout, ca_bout,
        ff_w1, ff_b1, ff_w2, ff_b2,
        query_embed, fc_rot_w, fc_rot_b, fc_trans_w, fc_trans_b,
        (const short*)d_ws, (float*)d_out);
  } else {
    hipFuncSetAttribute(reinterpret_cast<const void*>(&pose_kernel<false>),
                        hipFuncAttributeMaxDynamicSharedMemorySize, SMEM_TOTAL);
    pose_kernel<false><<<grid, NT, SMEM_TOTAL, stream>>>(
        feature1, feature2,
        sa1_win, sa1_bin, sa1_wout, sa1_bout,
        sa2_win, sa2_bin, sa2_wout, sa2_bout,
        ca_win, ca_bin, ca_wout, ca_bout,
        ff_w1, ff_b1, ff_w2, ff_b2,
        query_embed, fc_rot_w, fc_rot_b, fc_trans_w, fc_trans_b,
        (const short*)d_ws, (float*)d_out);
  }
}

// Round 11
// 1322.995 us; speedup vs baseline: 1.7699x; 1.7699x over previous
//
#include <hip/hip_runtime.h>
#include <hip/hip_bf16.h>

namespace {

using bf16x8 = __attribute__((ext_vector_type(8))) short;
using f32x4  = __attribute__((ext_vector_type(4))) float;

constexpr int NL = 9, S = 7, BB = 8192;
constexpr int G = 8;            // sequences per block
constexpr int M = G * S;        // 56 token rows
constexpr int NT = 512;

// LDS layout (bytes)
constexpr int OFF_F1 = 0;       // fp32 [56][64] swizzled (32B granule)
constexpr int OFF_F2 = 14336;
constexpr int OFF_Q  = 28672;
constexpr int OFF_QB = 43008;   // bf16 [56][64] swizzled (16B granule)
constexpr int OFF_KB = 50176;   // bf16 [112][64] swizzled
constexpr int OFF_VT = 64512;   // bf16 V [64 d][128 kv] swizzled (16B granule)
constexpr int SMEM_TOTAL = 80896;   // <= 81920 -> 2 blocks/CU

__device__ __forceinline__ unsigned short f2bf(float f) {
  union { __hip_bfloat16 h; unsigned short s; } u;
  u.h = __float2bfloat16(f);
  return u.s;
}
__device__ __forceinline__ uint32_t pk2(float a, float b) {
  return (uint32_t)f2bf(a) | ((uint32_t)f2bf(b) << 16);
}
__device__ __forceinline__ int swzS(int r, int c) {   // fp32 [*][64]
  return r * 256 + ((((c >> 3) ^ (r & 7)) << 5) | ((c & 7) << 2));
}
__device__ __forceinline__ int swzB(int r, int c) {   // bf16 [*][64]
  return r * 128 + ((((c >> 3) ^ (r & 7)) << 4) | ((c & 7) << 1));
}
__device__ __forceinline__ int swzV(int d, int kv) {  // bf16 [64][128]
  return d * 256 + ((((kv >> 3) ^ (d & 7)) << 4) | ((kv & 7) << 1));
}
__device__ __forceinline__ int div7(int t) { return (t * 9363) >> 16; }  // t < 56

// state fp32 (swizzled) -> bf16x8 fragment: 8 consecutive k (k0 % 8 == 0)
__device__ __forceinline__ bf16x8 ldStateFrag(const char* base, int r, int k0) {
  const float4* p = (const float4*)(base + r * 256 + (((k0 >> 3) ^ (r & 7)) << 5));
  float4 x = p[0], y = p[1];
  union { bf16x8 v; uint32_t u[4]; } o;
  o.u[0] = pk2(x.x, x.y); o.u[1] = pk2(x.z, x.w);
  o.u[2] = pk2(y.x, y.y); o.u[3] = pk2(y.z, y.w);
  return o.v;
}
__device__ __forceinline__ bf16x8 ldBfFrag(const char* base, int r, int k0) {
  return *(const bf16x8*)(base + r * 128 + (((k0 >> 3) ^ (r & 7)) << 4));
}

// Swapped-operand GEMM over a 64(or 32)-K projection.
// Normal tiles (nt < VNT):   D = W x state^T  -> lane: token col, 4 consecutive
//   feature rows -> packed 8B stores; bias float4 into acc.
// V tiles (nt >= VNT):       D = state x W^T  -> lane: feature col, 4 tokens.
template <int MTOT, int NTOT, int KF, int WMG, int WNG, int VNT, bool WS,
          class BLD, class STN, class STV>
__device__ __forceinline__ void gemm_sw(const short* __restrict__ wbf,
                                        const float* __restrict__ wf,
                                        const float* __restrict__ bias,
                                        int ldK, int wid, int lane,
                                        BLD bld, STN stn, STV stv)
{
  const int wm = wid / WNG, wn = wid % WNG;
  const int q = lane & 15, gI = lane >> 4;
  constexpr int MPW = (MTOT + WMG - 1) / WMG;
  constexpr int NPW = NTOT / WNG;
  bf16x8 bfr[MPW][KF];
#pragma unroll
  for (int i = 0; i < MPW; ++i) {
    const int mt = wm * MPW + i;
    if (mt < MTOT) {
#pragma unroll
      for (int kf = 0; kf < KF; ++kf)
        bfr[i][kf] = bld(mt * 16 + q, kf * 32 + gI * 8);
    }
  }
#pragma unroll
  for (int j = 0; j < NPW; ++j) {
    const int nt = wn * NPW + j;
    bf16x8 afr[KF];
#pragma unroll
    for (int kf = 0; kf < KF; ++kf) {
      const int k0 = kf * 32 + gI * 8;
      if constexpr (WS) {
        afr[kf] = *(const bf16x8*)(wbf + (size_t)(nt * 16 + q) * ldK + k0);
      } else {
        const float* wp = wf + (size_t)(nt * 16 + q) * ldK + k0;
        float4 x = *(const float4*)wp, y = *(const float4*)(wp + 4);
        union { bf16x8 v; uint32_t u[4]; } o;
        o.u[0] = pk2(x.x, x.y); o.u[1] = pk2(x.z, x.w);
        o.u[2] = pk2(y.x, y.y); o.u[3] = pk2(y.z, y.w);
        afr[kf] = o.v;
      }
    }
    if (nt < VNT) {
      const float4 b4 = *(const float4*)(bias + nt * 16 + gI * 4);
#pragma unroll
      for (int i = 0; i < MPW; ++i) {
        const int mt = wm * MPW + i;
        if (mt < MTOT) {
          f32x4 acc = { b4.x, b4.y, b4.z, b4.w };
#pragma unroll
          for (int kf = 0; kf < KF; ++kf)
            acc = __builtin_amdgcn_mfma_f32_16x16x32_bf16(afr[kf], bfr[i][kf], acc, 0, 0, 0);
          stn(mt, nt, acc);
        }
      }
    } else {
      const float bv = bias[nt * 16 + q];
#pragma unroll
      for (int i = 0; i < MPW; ++i) {
        const int mt = wm * MPW + i;
        if (mt < MTOT) {
          f32x4 acc = { bv, bv, bv, bv };
#pragma unroll
          for (int kf = 0; kf < KF; ++kf)
            acc = __builtin_amdgcn_mfma_f32_16x16x32_bf16(bfr[i][kf], afr[kf], acc, 0, 0, 0);
          stv(mt, nt, acc);
        }
      }
    }
  }
}

// Attention: wave wid owns sequence g = wid, loops over 4 heads.
template <bool CA_>
__device__ __forceinline__ void attn(char* qb, const char* kb, const char* vt,
                                     int wid, int lane)
{
  const int q = lane & 15, gI = lane >> 4;
  const int g = wid;
  constexpr int KVL = CA_ ? 14 : 7;
#pragma unroll
  for (int h = 0; h < 4; ++h) {
    bf16x8 kfrag = {}, qfrag = {};
    if (gI < 2) {
      int qrow = g * 7 + q; qrow = qrow > 55 ? 55 : qrow;
      qfrag = ldBfFrag(qb, qrow, h * 16 + gI * 8);
      int kvr;
      if constexpr (CA_) {
        kvr = (q < 7) ? (g * 7 + q) : (49 + g * 7 + q);
        kvr = kvr > 111 ? 111 : kvr;
      } else {
        kvr = g * 7 + q; kvr = kvr > 55 ? 55 : kvr;
      }
      kfrag = ldBfFrag(kb, kvr, h * 16 + gI * 8);
    }
    f32x4 s = { 0.f, 0.f, 0.f, 0.f };
    s = __builtin_amdgcn_mfma_f32_16x16x32_bf16(kfrag, qfrag, s, 0, 0, 0);

    float e[4]; float sum = 0.f;
#pragma unroll
    for (int jj = 0; jj < 4; ++jj) {
      const int kvloc = gI * 4 + jj;
      const float tt = fminf(s[jj] * 0.36067376f, 60.f);   // *0.25 * log2(e)
      e[jj] = (kvloc < KVL) ? exp2f(tt) : 0.f;
      sum += e[jj];
    }
    sum += __shfl_xor(sum, 16);
    sum += __shfl_xor(sum, 32);
    const float inv = __builtin_amdgcn_rcpf(sum);

    union { bf16x8 v; uint32_t u[4]; } pb;
    pb.u[0] = pk2(e[0] * inv, e[1] * inv);
    pb.u[1] = pk2(e[2] * inv, e[3] * inv);
    pb.u[2] = 0; pb.u[3] = 0;

    const int d = h * 16 + q;
    const int kv0 = (CA_ ? g * 16 : g * 8) + gI * 4;
    const uint2 vv = *(const uint2*)(vt + swzV(d, kv0));
    union { bf16x8 v; uint32_t u[4]; } va;
    va.u[0] = vv.x; va.u[1] = vv.y; va.u[2] = 0; va.u[3] = 0;

    f32x4 o = { 0.f, 0.f, 0.f, 0.f };
    o = __builtin_amdgcn_mfma_f32_16x16x32_bf16(va.v, pb.v, o, 0, 0, 0);

    if (q < 7) {
      const int tok = g * 7 + q, c0 = h * 16 + gI * 4;
      *(uint2*)(qb + swzB(tok, c0)) = make_uint2(pk2(o[0], o[1]), pk2(o[2], o[3]));
    }
  }
}

template <bool WS>
__global__ __launch_bounds__(NT, 4) void pose_kernel(
    const float* __restrict__ feature1, const float* __restrict__ feature2,
    const float* __restrict__ sa1_win, const float* __restrict__ sa1_bin,
    const float* __restrict__ sa1_wout, const float* __restrict__ sa1_bout,
    const float* __restrict__ sa2_win, const float* __restrict__ sa2_bin,
    const float* __restrict__ sa2_wout, const float* __restrict__ sa2_bout,
    const float* __restrict__ ca_win, const float* __restrict__ ca_bin,
    const float* __restrict__ ca_wout, const float* __restrict__ ca_bout,
    const float* __restrict__ ff_w1, const float* __restrict__ ff_b1,
    const float* __restrict__ ff_w2, const float* __restrict__ ff_b2,
    const float* __restrict__ query_embed,
    const float* __restrict__ fc_rot_w, const float* __restrict__ fc_rot_b,
    const float* __restrict__ fc_trans_w, const float* __restrict__ fc_trans_b,
    const short* __restrict__ wbf, float* __restrict__ out)
{
  extern __shared__ char smem[];
  char* sF1 = smem + OFF_F1;
  char* sF2 = smem + OFF_F2;
  char* sQ  = smem + OFF_Q;
  char* qb  = smem + OFF_QB;
  char* kb  = smem + OFF_KB;
  char* vt  = smem + OFF_VT;

  const int t = threadIdx.x;
  const int wid = t >> 6, lane = t & 63;
  const int q = lane & 15, gI = lane >> 4;

  // XCD-branch partitioning (bijective): assuming round-robin blockIdx->XCD,
  // branch 0 lands on XCDs 0-3 and branch 1 on XCDs 4-7, so each XCD's L2
  // holds only ONE branch's weight set (~1 MB) -> stays resident.
  const int flat = blockIdx.x;                 // 0 .. 2047
  const int xcd  = flat & 7, slot = flat >> 3;
  const int bi   = xcd >> 2;
  const int b0   = (((xcd & 3) | (slot << 2))) * G;

  // zero-init V buffer once (pad slots must be finite: NaN*0 = NaN in MFMA)
  {
    const uint4 z = { 0, 0, 0, 0 };
    for (int i = t; i < 1024; i += NT) ((uint4*)vt)[i] = z;
  }
  // load per-sequence state (coalesced, NON-TEMPORAL: features are read once
  // and must not evict the L2-resident weights)
  {
    const float* f1p = feature1 + (size_t)b0 * (S * 64);
    const float* f2p = feature2 + (size_t)b0 * (S * 64);
    const float* qe  = query_embed + (size_t)bi * (S * 64);
    for (int idx = t; idx < M * 64; idx += NT) {
      const int r = idx >> 6, c = idx & 63;
      const int s = r - div7(r) * 7;
      *(float*)(sF1 + swzS(r, c)) = __builtin_nontemporal_load(f1p + idx);
      *(float*)(sF2 + swzS(r, c)) = __builtin_nontemporal_load(f2p + idx);
      *(float*)(sQ + swzS(r, c))  = qe[s * 64 + c];
    }
  }
  __syncthreads();

  const auto stv_none = [](int, int, f32x4) {};

  for (int li = 0; li < NL; ++li) {
    const int wo = bi * NL + li;
    const short* W_in[3]  = { wbf + 0      + wo * 12288,
                              wbf + 221184 + wo * 12288,
                              wbf + 442368 + wo * 12288 };
    const short* W_out[3] = { wbf + 663552 + wo * 4096,
                              wbf + 737280 + wo * 4096,
                              wbf + 811008 + wo * 4096 };
    const short* W_f1 = wbf + 884736 + wo * 2048;
    const short* W_f2 = wbf + 921600 + wo * 2048;
    const float* F_in[3]  = { sa1_win + wo * 12288, sa2_win + wo * 12288, ca_win + wo * 12288 };
    const float* F_out[3] = { sa1_wout + wo * 4096, sa2_wout + wo * 4096, ca_wout + wo * 4096 };
    const float* B_in[3]  = { sa1_bin + wo * 192, sa2_bin + wo * 192, ca_bin + wo * 192 };
    const float* B_out[3] = { sa1_bout + wo * 64, sa2_bout + wo * 64, ca_bout + wo * 64 };

    // ---------- self-attention on f1, then f2 ----------
    for (int sa = 0; sa < 2; ++sa) {
      char* ST = sa ? sF2 : sF1;
      auto bld = [&](int r, int k0) { return ldStateFrag(ST, r > 55 ? 55 : r, k0); };
      auto stn = [&](int mt, int nt, f32x4 a) {        // nt<4: Q, 4..7: K
        const int tok = mt * 16 + q; if (tok >= M) return;
        if (nt < 4) {
          *(uint2*)(qb + swzB(tok, nt * 16 + gI * 4)) =
              make_uint2(pk2(a[0], a[1]), pk2(a[2], a[3]));
        } else {
          *(uint2*)(kb + swzB(tok, (nt - 4) * 16 + gI * 4)) =
              make_uint2(pk2(a[0], a[1]), pk2(a[2], a[3]));
        }
      };
      auto stv = [&](int mt, int nt, f32x4 a) {        // nt>=8: V -> vt[d][kv]
        const int d = (nt - 8) * 16 + q;
#pragma unroll
        for (int jj = 0; jj < 4; ++jj) {
          const int tok = mt * 16 + gI * 4 + jj;
          if (tok < M) {
            const int g = div7(tok);
            *(short*)(vt + swzV(d, g * 8 + (tok - g * 7))) = (short)f2bf(a[jj]);
          }
        }
      };
      gemm_sw<4, 12, 2, 2, 4, 8, WS>(W_in[sa], F_in[sa], B_in[sa], 64, wid, lane, bld, stn, stv);
      __syncthreads();
      attn<false>(qb, kb, vt, wid, lane);
      __syncthreads();
      auto bldc = [&](int r, int k0) { return ldBfFrag(qb, r > 55 ? 55 : r, k0); };
      auto stres = [&](int mt, int nt, f32x4 a) {
        const int tok = mt * 16 + q; if (tok >= M) return;
        const int c0 = nt * 16 + gI * 4;
        float4* p = (float4*)(ST + tok * 256 + (((c0 >> 3) ^ (tok & 7)) << 5) + (c0 & 7) * 4);
        float4 v = *p;
        v.x += a[0]; v.y += a[1]; v.z += a[2]; v.w += a[3];
        *p = v;
      };
      gemm_sw<4, 4, 2, 2, 4, 4, WS>(W_out[sa], F_out[sa], B_out[sa], 64, wid, lane, bldc, stres, stv_none);
      __syncthreads();
    }

    // ---------- cross-attention ----------
    {
      auto bldq = [&](int r, int k0) { return ldStateFrag(sQ, r > 55 ? 55 : r, k0); };
      auto stq = [&](int mt, int nt, f32x4 a) {
        const int tok = mt * 16 + q; if (tok >= M) return;
        *(uint2*)(qb + swzB(tok, nt * 16 + gI * 4)) =
            make_uint2(pk2(a[0], a[1]), pk2(a[2], a[3]));
      };
      gemm_sw<4, 4, 2, 2, 4, 4, WS>(W_in[2], F_in[2], B_in[2], 64, wid, lane, bldq, stq, stv_none);

      for (int src = 0; src < 2; ++src) {
        const char* SRC = src ? sF2 : sF1;
        auto bld = [&](int r, int k0) { return ldStateFrag(SRC, r > 55 ? 55 : r, k0); };
        auto stk = [&](int mt, int nt, f32x4 a) {      // nt<4: K
          const int tok = mt * 16 + q; if (tok >= M) return;
          *(uint2*)(kb + swzB(tok + src * 56, nt * 16 + gI * 4)) =
              make_uint2(pk2(a[0], a[1]), pk2(a[2], a[3]));
        };
        auto stv = [&](int mt, int nt, f32x4 a) {      // nt>=4: V
          const int d = (nt - 4) * 16 + q;
#pragma unroll
          for (int jj = 0; jj < 4; ++jj) {
            const int tok = mt * 16 + gI * 4 + jj;
            if (tok < M) {
              const int g = div7(tok);
              *(short*)(vt + swzV(d, g * 16 + (tok - g * 7) + src * 7)) = (short)f2bf(a[jj]);
            }
          }
        };
        gemm_sw<4, 8, 2, 2, 4, 4, WS>(W_in[2] + 4096, F_in[2] + 4096, B_in[2] + 64,
                                      64, wid, lane, bld, stk, stv);
      }
      __syncthreads();
      attn<true>(qb, kb, vt, wid, lane);
      __syncthreads();
      auto bldc = [&](int r, int k0) { return ldBfFrag(qb, r > 55 ? 55 : r, k0); };
      auto stres = [&](int mt, int nt, f32x4 a) {
        const int tok = mt * 16 + q; if (tok >= M) return;
        const int c0 = nt * 16 + gI * 4;
        float4* p = (float4*)(sQ + tok * 256 + (((c0 >> 3) ^ (tok & 7)) << 5) + (c0 & 7) * 4);
        float4 v = *p;
        v.x += a[0]; v.y += a[1]; v.z += a[2]; v.w += a[3];
        *p = v;
      };
      gemm_sw<4, 4, 2, 2, 4, 4, WS>(W_out[2], F_out[2], B_out[2], 64, wid, lane, bldc, stres, stv_none);
      __syncthreads();
    }

    // ---------- FFN ----------
    {
      auto bldq = [&](int r, int k0) { return ldStateFrag(sQ, r > 55 ? 55 : r, k0); };
      auto sth = [&](int mt, int nt, f32x4 a) {        // relu -> qb cols 0..31
        const int tok = mt * 16 + q; if (tok >= M) return;
        *(uint2*)(qb + swzB(tok, nt * 16 + gI * 4)) =
            make_uint2(pk2(fmaxf(a[0], 0.f), fmaxf(a[1], 0.f)),
                       pk2(fmaxf(a[2], 0.f), fmaxf(a[3], 0.f)));
      };
      gemm_sw<4, 2, 2, 4, 2, 2, WS>(W_f1, ff_w1 + wo * 2048, ff_b1 + wo * 32,
                                    64, wid, lane, bldq, sth, stv_none);
      __syncthreads();
      auto bldh = [&](int r, int k0) { return ldBfFrag(qb, r > 55 ? 55 : r, k0); };
      auto stres = [&](int mt, int nt, f32x4 a) {
        const int tok = mt * 16 + q; if (tok >= M) return;
        const int c0 = nt * 16 + gI * 4;
        float4* p = (float4*)(sQ + tok * 256 + (((c0 >> 3) ^ (tok & 7)) << 5) + (c0 & 7) * 4);
        float4 v = *p;
        v.x += a[0]; v.y += a[1]; v.z += a[2]; v.w += a[3];
        *p = v;
      };
      gemm_sw<4, 4, 1, 2, 4, 4, WS>(W_f2, ff_w2 + wo * 2048, ff_b2 + wo * 64,
                                    32, wid, lane, bldh, stres, stv_none);
      __syncthreads();
    }
  }

  // ---------- pose head ----------
  float* cs = (float*)qb;   // [8][64] fp32 scratch (qb is free now)
  {
    const int g = t >> 6, c = t & 63;   // 512 threads == 8*64 items
    float a = 0.f;
#pragma unroll
    for (int s = 0; s < 7; ++s) a += *(const float*)(sQ + swzS(g * 7 + s, c));
    cs[t] = a;
  }
  __syncthreads();
  const int ncols = bi ? 3 : 4;
  if (t < G * ncols) {
    const int g = t / ncols, cc = t - g * ncols;
    const float* wv = bi ? (fc_trans_w + cc * 64) : (fc_rot_w + cc * 64);
    float acc = 0.f;
#pragma unroll
    for (int k = 0; k < 64; ++k) acc += cs[g * 64 + k] * wv[k];
    const float bb = bi ? fc_trans_b[cc] : fc_rot_b[cc];
    __builtin_nontemporal_store(acc * (1.f / 7.f) + bb,
        out + (size_t)(b0 + g) * 7 + (bi ? 4 : 0) + cc);
  }
}

// Convert all weight matrices fp32 -> bf16 into workspace (once per call).
__global__ void prep_kernel(const float* __restrict__ a0, const float* __restrict__ a1,
                            const float* __restrict__ a2, const float* __restrict__ a3,
                            const float* __restrict__ a4, const float* __restrict__ a5,
                            const float* __restrict__ a6, const float* __restrict__ a7,
                            short* __restrict__ dst)
{
  for (int i = blockIdx.x * blockDim.x + threadIdx.x; i < 958464;
       i += gridDim.x * blockDim.x) {
    const float* s; int j;
    if      (i < 221184) { s = a0; j = i; }
    else if (i < 442368) { s = a1; j = i - 221184; }
    else if (i < 663552) { s = a2; j = i - 442368; }
    else if (i < 737280) { s = a3; j = i - 663552; }
    else if (i < 811008) { s = a4; j = i - 737280; }
    else if (i < 884736) { s = a5; j = i - 811008; }
    else if (i < 921600) { s = a6; j = i - 884736; }
    else                 { s = a7; j = i - 921600; }
    dst[i] = (short)f2bf(s[j]);
  }
}

} // namespace

extern "C" void kernel_launch(void* const* d_in, const int* in_sizes, int n_in,
                              void* d_out, int out_size, void* d_ws, size_t ws_size,
                              hipStream_t stream)
{
  const float* feature1    = (const float*)d_in[0];
  const float* feature2    = (const float*)d_in[1];
  const float* sa1_win     = (const float*)d_in[2];
  const float* sa1_bin     = (const float*)d_in[3];
  const float* sa1_wout    = (const float*)d_in[4];
  const float* sa1_bout    = (const float*)d_in[5];
  const float* sa2_win     = (const float*)d_in[6];
  const float* sa2_bin     = (const float*)d_in[7];
  const float* sa2_wout    = (const float*)d_in[8];
  const float* sa2_bout    = (const float*)d_in[9];
  const float* ca_win      = (const float*)d_in[10];
  const float* ca_bin      = (const float*)d_in[11];
  const float* ca_wout     = (const float*)d_in[12];
  const float* ca_bout     = (const float*)d_in[13];
  const float* ff_w1       = (const float*)d_in[14];
  const float* ff_b1       = (const float*)d_in[15];
  const float* ff_w2       = (const float*)d_in[16];
  const float* ff_b2       = (const float*)d_in[17];
  const float* query_embed = (const float*)d_in[18];
  const float* fc_rot_w    = (const float*)d_in[19];
  const float* fc_rot_b    = (const float*)d_in[20];
  const float* fc_trans_w  = (const float*)d_in[21];
  const float* fc_trans_b  = (const float*)d_in[22];

  const bool ws_ok = (d_ws != nullptr) && (ws_size >= (size_t)958464 * 2);
  dim3 grid((BB / G) * 2);   // 1-D: (branch, seq-block) derived in-kernel

  if (ws_ok) {
    prep_kernel<<<dim3(936), 512, 0, stream>>>(sa1_win, sa2_win, ca_win,
                                               sa1_wout, sa2_wout, ca_wout,
                                               ff_w1, ff_w2, (short*)d_ws);
    hipFuncSetAttribute(reinterpret_cast<const void*>(&pose_kernel<true>),
                        hipFuncAttributeMaxDynamicSharedMemorySize, SMEM_TOTAL);
    pose_kernel<true><<<grid, NT, SMEM_TOTAL, stream>>>(
        feature1, feature2,
        sa1_win, sa1_bin, sa1_wout, sa1_bout,
        sa2_win, sa2_bin, sa2_wout, sa2_bout,
        ca_win, ca_bin, ca_wout, ca_bout,
        ff_w1, ff_b1, ff_w2, ff_b2,
        query_embed, fc_rot_w, fc_rot_b, fc_trans_w, fc_trans_b,
        (const short*)d_ws, (float*)d_out);
  } else {
    hipFuncSetAttribute(reinterpret_cast<const void*>(&pose_kernel<false>),
                        hipFuncAttributeMaxDynamicSharedMemorySize, SMEM_TOTAL);
    pose_kernel<false><<<grid, NT, SMEM_TOTAL, stream>>>(
        feature1, feature2,
        sa1_win, sa1_bin, sa1_wout, sa1_bout,
        sa2_win, sa2_bin, sa2_wout, sa2_bout,
        ca_win, ca_bin, ca_wout, ca_bout,
        ff_w1, ff_b1, ff_w2, ff_b2,
        query_embed, fc_rot_w, fc_rot_b, fc_trans_w, fc_trans_b,
        (const short*)d_ws, (float*)d_out);
  }
}